// Round 1
// baseline (84.495 us; speedup 1.0000x reference)
//
#include <hip/hip_runtime.h>
#include <math.h>

// GCN actor collapses: complete graph + self loops + unit edge weights
// => deg==32 everywhere, norm==1/32 => GCN aggregation == per-sample mean.
// After layer 1 all 32 nodes of a sample are identical, so layer 2's
// aggregation is the identity. Entire net = per-sample 14->128->128->128->4 MLP.

constexpr int NODES = 32;
constexpr int OBSD  = 16;
constexpr int FEAT  = 14;   // obs[:, 2:16]
constexpr int H     = 128;
constexpr int SPB   = 4;    // samples per block (weight-load reuse factor)
constexpr int TPB   = 128;

__global__ __launch_bounds__(TPB) void gcn_actor(
    const float* __restrict__ obs,
    const float* __restrict__ W1,  const float* __restrict__ b1,
    const float* __restrict__ W2,  const float* __restrict__ b2,
    const float* __restrict__ Wm1, const float* __restrict__ bm1,
    const float* __restrict__ Wm2, const float* __restrict__ bm2,
    float* __restrict__ out, int bs)
{
    const int tid = threadIdx.x;
    const int s0  = blockIdx.x * SPB;

    __shared__ float s_obs[SPB * NODES * OBSD];   // 2048 floats
    __shared__ float s_mean[SPB][FEAT];
    __shared__ float s_ga[SPB][H];
    __shared__ float s_gb[SPB][H];
    __shared__ float s_o[SPB][4];

    // ---- Phase 1a: stage 4 samples of obs (contiguous 2048 floats) ----
    {
        const float4* gsrc = reinterpret_cast<const float4*>(obs + (size_t)s0 * NODES * OBSD);
        float4* ldst = reinterpret_cast<float4*>(s_obs);
        #pragma unroll
        for (int i = 0; i < (SPB * NODES * OBSD / 4) / TPB; ++i)   // 4 iters
            ldst[tid + i * TPB] = gsrc[tid + i * TPB];
    }
    __syncthreads();

    // ---- Phase 1b: per-sample column means over nodes (cols 2..15) ----
    if (tid < SPB * FEAT) {
        const int s = tid / FEAT, c = tid % FEAT;
        float acc = 0.f;
        const float* p = s_obs + s * NODES * OBSD + 2 + c;
        #pragma unroll
        for (int n = 0; n < NODES; ++n) acc += p[n * OBSD];
        s_mean[s][c] = acc * (1.0f / NODES);
    }
    __syncthreads();

    // ---- Phase 2: g1 = relu(mean @ W1 + b1) -> s_ga ----
    {
        float acc[SPB];
        const float bb = b1[tid];
        #pragma unroll
        for (int s = 0; s < SPB; ++s) acc[s] = bb;
        #pragma unroll
        for (int k = 0; k < FEAT; ++k) {
            const float w = W1[k * H + tid];
            #pragma unroll
            for (int s = 0; s < SPB; ++s) acc[s] = fmaf(w, s_mean[s][k], acc[s]);
        }
        #pragma unroll
        for (int s = 0; s < SPB; ++s) s_ga[s][tid] = fmaxf(acc[s], 0.f);
    }
    __syncthreads();

    // ---- Phase 3: g2 = relu(g1 @ W2 + b2) -> s_gb ----
    {
        float acc[SPB];
        const float bb = b2[tid];
        #pragma unroll
        for (int s = 0; s < SPB; ++s) acc[s] = bb;
        #pragma unroll 8
        for (int k = 0; k < H; ++k) {
            const float w = W2[k * H + tid];          // coalesced; L1/L2-hot
            #pragma unroll
            for (int s = 0; s < SPB; ++s) acc[s] = fmaf(w, s_ga[s][k], acc[s]);  // LDS broadcast
        }
        #pragma unroll
        for (int s = 0; s < SPB; ++s) s_gb[s][tid] = fmaxf(acc[s], 0.f);
    }
    __syncthreads();

    // ---- Phase 4: m = relu(g2 @ Wm1 + bm1) -> s_ga ----
    {
        float acc[SPB];
        const float bb = bm1[tid];
        #pragma unroll
        for (int s = 0; s < SPB; ++s) acc[s] = bb;
        #pragma unroll 8
        for (int k = 0; k < H; ++k) {
            const float w = Wm1[k * H + tid];
            #pragma unroll
            for (int s = 0; s < SPB; ++s) acc[s] = fmaf(w, s_gb[s][k], acc[s]);
        }
        #pragma unroll
        for (int s = 0; s < SPB; ++s) s_ga[s][tid] = fmaxf(acc[s], 0.f);
    }
    __syncthreads();

    // ---- Phase 5: o = m @ Wm2 + bm2; squash tail ----
    if (tid < SPB * 4) {
        const int s = tid / 4, c = tid % 4;
        float acc = bm2[c];
        #pragma unroll 8
        for (int k = 0; k < H; ++k) acc = fmaf(s_ga[s][k], Wm2[k * 4 + c], acc);
        if (c >= 2) {
            const float t  = tanhf(acc);
            const float ls = -5.0f + 3.5f * (t + 1.0f);   // LOG_STD_MIN + 0.5*range*(t+1)
            acc = expf(ls);
        }
        s_o[s][c] = acc;
    }
    __syncthreads();

    // ---- Phase 6: write out (2, bs, 64); each sample's 64 = (o0,o1) x 32 ----
    {
        const int half = tid >> 6;          // 0 = mu, 1 = std
        const int t    = tid & 63;          // float4 index within 256-float region
        const int s    = t >> 4;            // 16 float4 per sample
        const float v0 = s_o[s][half * 2 + 0];
        const float v1 = s_o[s][half * 2 + 1];
        float4* dst = reinterpret_cast<float4*>(out + (size_t)half * bs * 64 + (size_t)s0 * 64);
        dst[t] = make_float4(v0, v1, v0, v1);
    }
}

extern "C" void kernel_launch(void* const* d_in, const int* in_sizes, int n_in,
                              void* d_out, int out_size, void* d_ws, size_t ws_size,
                              hipStream_t stream) {
    const float* obs = (const float*)d_in[0];
    const float* W1  = (const float*)d_in[1];
    const float* b1  = (const float*)d_in[2];
    const float* W2  = (const float*)d_in[3];
    const float* b2  = (const float*)d_in[4];
    const float* Wm1 = (const float*)d_in[5];
    const float* bm1 = (const float*)d_in[6];
    const float* Wm2 = (const float*)d_in[7];
    const float* bm2 = (const float*)d_in[8];
    float* out = (float*)d_out;

    const int bs   = in_sizes[0] / (NODES * OBSD);   // 1024
    const int grid = bs / SPB;                       // 256

    gcn_actor<<<grid, TPB, 0, stream>>>(obs, W1, b1, W2, b2, Wm1, bm1, Wm2, bm2, out, bs);
}

// Round 2
// 74.456 us; speedup vs baseline: 1.1348x; 1.1348x over previous
//
#include <hip/hip_runtime.h>
#include <math.h>

// GCN actor collapses: complete graph + self loops + unit edge weights
// => deg==32 everywhere, norm==1/32 => GCN aggregation == per-sample mean.
// After layer 1 all 32 nodes of a sample are identical, so layer 2's
// aggregation is the identity. Entire net = per-sample 14->128->128->128->4 MLP.
//
// R2 structure: 512 thr/block (8 waves/CU), K split across 4 groups
// (k-loop 128->32 iters) + LDS partial reduce; head via shfl reduction.

constexpr int NODES = 32;
constexpr int OBSD  = 16;
constexpr int FEAT  = 14;   // obs[:, 2:16]
constexpr int H     = 128;
constexpr int SPB   = 4;    // samples per block
constexpr int TPB   = 512;  // (n = tid&127, q = tid>>7): q = k-quarter

__global__ __launch_bounds__(TPB) void gcn_actor(
    const float* __restrict__ obs,
    const float* __restrict__ W1,  const float* __restrict__ b1,
    const float* __restrict__ W2,  const float* __restrict__ b2,
    const float* __restrict__ Wm1, const float* __restrict__ bm1,
    const float* __restrict__ Wm2, const float* __restrict__ bm2,
    float* __restrict__ out, int bs)
{
    const int tid = threadIdx.x;
    const int s0  = blockIdx.x * SPB;
    const int n   = tid & (H - 1);   // neuron
    const int q   = tid >> 7;        // k-quarter [0,4)

    __shared__ float s_obs[SPB * NODES * OBSD];   // 8 KB
    __shared__ float s_mean[SPB][FEAT];
    __shared__ float s_part[4][SPB][H];           // 8 KB partial sums
    __shared__ float s_x[SPB][H];                 // activation ping
    __shared__ float s_y[SPB][H];                 // activation pong
    __shared__ float s_o[SPB][4];

    // ---- stage 4 samples of obs: 512 float4, one per thread ----
    {
        const float4* g = reinterpret_cast<const float4*>(obs + (size_t)s0 * NODES * OBSD);
        reinterpret_cast<float4*>(s_obs)[tid] = g[tid];
    }
    __syncthreads();

    // ---- per-sample node means, cols 2..15: 224 threads x 8 nodes, then 56 combine ----
    if (tid < SPB * FEAT * 4) {
        const int p = tid & 3, cs = tid >> 2;
        const int s = cs / FEAT, c = cs - s * FEAT;
        const float* base = s_obs + s * NODES * OBSD + 2 + c;
        float a = 0.f;
        #pragma unroll
        for (int j = 0; j < 8; ++j) a += base[(p * 8 + j) * OBSD];
        reinterpret_cast<float*>(s_part)[tid] = a;
    }
    __syncthreads();
    if (tid < SPB * FEAT) {
        float a = 0.f;
        #pragma unroll
        for (int p = 0; p < 4; ++p) a += reinterpret_cast<float*>(s_part)[tid * 4 + p];
        const int s = tid / FEAT, c = tid - s * FEAT;
        s_mean[s][c] = a * (1.0f / NODES);
    }
    __syncthreads();

    // ---- L1: mean(14) @ W1 -> s_x ; K split 4/4/4/2 across q ----
    {
        float acc[SPB] = {0.f, 0.f, 0.f, 0.f};
        const int k0 = q * 4;
        const int kc = (FEAT - k0 < 4) ? (FEAT - k0) : 4;
        for (int i = 0; i < kc; ++i) {
            const int k = k0 + i;
            const float w = W1[k * H + n];
            #pragma unroll
            for (int s = 0; s < SPB; ++s) acc[s] = fmaf(w, s_mean[s][k], acc[s]);
        }
        #pragma unroll
        for (int s = 0; s < SPB; ++s) s_part[q][s][n] = acc[s];
    }
    __syncthreads();
    {
        const int s2 = tid >> 7, n2 = tid & (H - 1);
        float v = b1[n2];
        #pragma unroll
        for (int qq = 0; qq < 4; ++qq) v += s_part[qq][s2][n2];
        s_x[s2][n2] = fmaxf(v, 0.f);
    }
    __syncthreads();

    // ---- L2: s_x @ W2 -> s_y ; 32 k-iters per thread ----
    {
        float acc[SPB] = {0.f, 0.f, 0.f, 0.f};
        const int kbase = q * 32;
        #pragma unroll
        for (int i = 0; i < 8; ++i) {
            const int k = kbase + i * 4;
            const float w0 = W2[(k + 0) * H + n];
            const float w1 = W2[(k + 1) * H + n];
            const float w2 = W2[(k + 2) * H + n];
            const float w3 = W2[(k + 3) * H + n];
            #pragma unroll
            for (int s = 0; s < SPB; ++s) {
                const float4 xv = *reinterpret_cast<const float4*>(&s_x[s][k]);
                acc[s] = fmaf(w3, xv.w, fmaf(w2, xv.z, fmaf(w1, xv.y, fmaf(w0, xv.x, acc[s]))));
            }
        }
        #pragma unroll
        for (int s = 0; s < SPB; ++s) s_part[q][s][n] = acc[s];
    }
    __syncthreads();
    {
        const int s2 = tid >> 7, n2 = tid & (H - 1);
        float v = b2[n2];
        #pragma unroll
        for (int qq = 0; qq < 4; ++qq) v += s_part[qq][s2][n2];
        s_y[s2][n2] = fmaxf(v, 0.f);
    }
    __syncthreads();

    // ---- L3: s_y @ Wm1 -> s_x ----
    {
        float acc[SPB] = {0.f, 0.f, 0.f, 0.f};
        const int kbase = q * 32;
        #pragma unroll
        for (int i = 0; i < 8; ++i) {
            const int k = kbase + i * 4;
            const float w0 = Wm1[(k + 0) * H + n];
            const float w1 = Wm1[(k + 1) * H + n];
            const float w2 = Wm1[(k + 2) * H + n];
            const float w3 = Wm1[(k + 3) * H + n];
            #pragma unroll
            for (int s = 0; s < SPB; ++s) {
                const float4 xv = *reinterpret_cast<const float4*>(&s_y[s][k]);
                acc[s] = fmaf(w3, xv.w, fmaf(w2, xv.z, fmaf(w1, xv.y, fmaf(w0, xv.x, acc[s]))));
            }
        }
        #pragma unroll
        for (int s = 0; s < SPB; ++s) s_part[q][s][n] = acc[s];
    }
    __syncthreads();
    {
        const int s2 = tid >> 7, n2 = tid & (H - 1);
        float v = bm1[n2];
        #pragma unroll
        for (int qq = 0; qq < 4; ++qq) v += s_part[qq][s2][n2];
        s_x[s2][n2] = fmaxf(v, 0.f);
    }
    __syncthreads();

    // ---- head: o[s][c] = m @ Wm2 + bm2 ; 32-lane partial dots + shfl reduce ----
    {
        const int p5 = tid & 31;          // k-chunk [0,32), 4 k's each
        const int c5 = (tid >> 5) & 3;    // output column
        const int s5 = tid >> 7;          // sample
        const float4 mv = reinterpret_cast<const float4*>(s_x[s5])[p5];
        const int k = p5 * 4;
        float acc = mv.x * Wm2[(k + 0) * 4 + c5];
        acc = fmaf(mv.y, Wm2[(k + 1) * 4 + c5], acc);
        acc = fmaf(mv.z, Wm2[(k + 2) * 4 + c5], acc);
        acc = fmaf(mv.w, Wm2[(k + 3) * 4 + c5], acc);
        #pragma unroll
        for (int m = 16; m; m >>= 1) acc += __shfl_xor(acc, m, 64);
        if (p5 == 0) {
            float v = acc + bm2[c5];
            if (c5 >= 2) {
                const float t = tanhf(v);
                v = expf(-5.0f + 3.5f * (t + 1.0f));  // exp(LOG_STD_MIN + 0.5*range*(t+1))
            }
            s_o[s5][c5] = v;
        }
    }
    __syncthreads();

    // ---- write out (2, bs, 64); sample's 64 = (o0,o1) x 32 nodes ----
    if (tid < 128) {
        const int half = tid >> 6;        // 0 = mu, 1 = std
        const int t    = tid & 63;        // float4 index within this block's region
        const int s    = t >> 4;          // 16 float4 per sample
        const float v0 = s_o[s][half * 2 + 0];
        const float v1 = s_o[s][half * 2 + 1];
        float4* dst = reinterpret_cast<float4*>(out + (size_t)half * bs * 64 + (size_t)s0 * 64);
        dst[t] = make_float4(v0, v1, v0, v1);
    }
}

extern "C" void kernel_launch(void* const* d_in, const int* in_sizes, int n_in,
                              void* d_out, int out_size, void* d_ws, size_t ws_size,
                              hipStream_t stream) {
    const float* obs = (const float*)d_in[0];
    const float* W1  = (const float*)d_in[1];
    const float* b1  = (const float*)d_in[2];
    const float* W2  = (const float*)d_in[3];
    const float* b2  = (const float*)d_in[4];
    const float* Wm1 = (const float*)d_in[5];
    const float* bm1 = (const float*)d_in[6];
    const float* Wm2 = (const float*)d_in[7];
    const float* bm2 = (const float*)d_in[8];
    float* out = (float*)d_out;

    const int bs   = in_sizes[0] / (NODES * OBSD);   // 1024
    const int grid = bs / SPB;                       // 256 blocks, 1/CU

    gcn_actor<<<grid, TPB, 0, stream>>>(obs, W1, b1, W2, b2, Wm1, bm1, Wm2, bm2, out, bs);
}